// Round 2
// baseline (1816.970 us; speedup 1.0000x reference)
//
#include <hip/hip_runtime.h>
#include <cstdint>

#define HN 64
#define HE 64
#define NNODE 50000
#define NEDGE 200000
#define NTRIP 600000
#define EPSBN 1e-5f

// gstats layout (floats): c2_sum(128) c2_sq(128) c3_sum(128) c3_sq(128)
//                         u_sum(64) u_sq(64) agg_sum(64) agg_sq(64)   = 768
// scales layout (floats): c2_scale(128) c2_shift(128) c3_scale(128) c3_shift(128)
//                         u_scale(64) u_shift(64) agg_scale(64) agg_shift(64) = 768

__device__ __forceinline__ float sigmoid_f(float x) {
    return 1.0f / (1.0f + __expf(-x));
}
__device__ __forceinline__ float tanh_f(float x) {
    return 1.0f - 2.0f / (__expf(2.0f * x) + 1.0f);
}

// ---------------------------------------------------------------------------
// c3 GEMM: C(T,128) = concat(node[ii],node[ij],node[ik],edge[ji],edge[kj]) @ W3^T
// BM=128, BN=128, BK=32, 256 threads, 8x8 acc/thread.
// MODE 0: column stats only.  MODE 1: store C + column stats.
// MODE 2: BN + sigmoid*tanh gate + atomic scatter into agg (no store of C).
// ---------------------------------------------------------------------------
template <int MODE>
__global__ __launch_bounds__(256) void k_gemm_c3(
    const float* __restrict__ node, const float* __restrict__ edge,
    const int* __restrict__ idx_i, const int* __restrict__ idx_j,
    const int* __restrict__ idx_k, const int* __restrict__ idx_ji,
    const int* __restrict__ idx_kj, const float* __restrict__ W3,
    float* __restrict__ out_lin, float* __restrict__ gsum, float* __restrict__ gsq,
    const float* __restrict__ scales, float* __restrict__ agg)
{
    __shared__ float sA[32][132];
    __shared__ float sB[32][132];
    __shared__ float sstat[256];

    const int tid = threadIdx.x;
    const int tx = tid & 15, ty = tid >> 4;
    const int bm = blockIdx.x * 128;

    float acc[8][8];
#pragma unroll
    for (int i = 0; i < 8; ++i)
#pragma unroll
        for (int j = 0; j < 8; ++j) acc[i][j] = 0.0f;

    const int mstage = tid >> 1;
    const int kq = (tid & 1) * 16;
    int g = bm + mstage;
    if (g >= NTRIP) g = NTRIP - 1;
    const int r0 = idx_i[g], r1 = idx_j[g], r2 = idx_k[g];
    const int r3 = idx_ji[g], r4 = idx_kj[g];

    for (int s = 0; s < 10; ++s) {
        const int seg = s >> 1;
        const int kin = (s & 1) * 32;
        const float* src;
        switch (seg) {
            case 0: src = node + (size_t)r0 * 64; break;
            case 1: src = node + (size_t)r1 * 64; break;
            case 2: src = node + (size_t)r2 * 64; break;
            case 3: src = edge + (size_t)r3 * 64; break;
            default: src = edge + (size_t)r4 * 64; break;
        }
        const float4* pa = reinterpret_cast<const float4*>(src + kin + kq);
        float4 v0 = pa[0], v1 = pa[1], v2 = pa[2], v3 = pa[3];
        const float4* pb = reinterpret_cast<const float4*>(
            W3 + (size_t)mstage * 320 + seg * 64 + kin + kq);
        float4 w0 = pb[0], w1 = pb[1], w2 = pb[2], w3 = pb[3];

        __syncthreads();  // prior tile's compute done before LDS overwrite
        const float va[16] = {v0.x,v0.y,v0.z,v0.w, v1.x,v1.y,v1.z,v1.w,
                              v2.x,v2.y,v2.z,v2.w, v3.x,v3.y,v3.z,v3.w};
        const float vb[16] = {w0.x,w0.y,w0.z,w0.w, w1.x,w1.y,w1.z,w1.w,
                              w2.x,w2.y,w2.z,w2.w, w3.x,w3.y,w3.z,w3.w};
#pragma unroll
        for (int u = 0; u < 16; ++u) sA[kq + u][mstage] = va[u];
#pragma unroll
        for (int u = 0; u < 16; ++u) sB[kq + u][mstage] = vb[u];
        __syncthreads();

#pragma unroll 4
        for (int k = 0; k < 32; ++k) {
            const float4 a0 = *reinterpret_cast<const float4*>(&sA[k][ty * 4]);
            const float4 a1 = *reinterpret_cast<const float4*>(&sA[k][64 + ty * 4]);
            const float4 b0 = *reinterpret_cast<const float4*>(&sB[k][tx * 4]);
            const float4 b1 = *reinterpret_cast<const float4*>(&sB[k][64 + tx * 4]);
            const float av[8] = {a0.x,a0.y,a0.z,a0.w, a1.x,a1.y,a1.z,a1.w};
            const float bv[8] = {b0.x,b0.y,b0.z,b0.w, b1.x,b1.y,b1.z,b1.w};
#pragma unroll
            for (int i = 0; i < 8; ++i)
#pragma unroll
                for (int j = 0; j < 8; ++j)
                    acc[i][j] = fmaf(av[i], bv[j], acc[i][j]);
        }
    }

    int rowg[8];
#pragma unroll
    for (int i = 0; i < 8; ++i) {
        const int m = (i < 4) ? (ty * 4 + i) : (64 + ty * 4 + (i - 4));
        rowg[i] = bm + m;
    }

    if (MODE == 1) {
#pragma unroll
        for (int i = 0; i < 8; ++i) {
            if (rowg[i] < NTRIP) {
                float4 s0 = make_float4(acc[i][0], acc[i][1], acc[i][2], acc[i][3]);
                float4 s1 = make_float4(acc[i][4], acc[i][5], acc[i][6], acc[i][7]);
                *reinterpret_cast<float4*>(&out_lin[(size_t)rowg[i] * 128 + tx * 4]) = s0;
                *reinterpret_cast<float4*>(&out_lin[(size_t)rowg[i] * 128 + 64 + tx * 4]) = s1;
            }
        }
    }

    if (MODE == 0 || MODE == 1) {
        __syncthreads();
        sstat[tid] = 0.0f;
        __syncthreads();
#pragma unroll
        for (int j = 0; j < 8; ++j) {
            const int n = (j < 4) ? (tx * 4 + j) : (64 + tx * 4 + (j - 4));
            float s = 0.0f, q = 0.0f;
#pragma unroll
            for (int i = 0; i < 8; ++i) {
                if (rowg[i] < NTRIP) { s += acc[i][j]; q += acc[i][j] * acc[i][j]; }
            }
            atomicAdd(&sstat[n], s);
            atomicAdd(&sstat[128 + n], q);
        }
        __syncthreads();
        if (tid < 128) {
            atomicAdd(&gsum[tid], sstat[tid]);
            atomicAdd(&gsq[tid], sstat[128 + tid]);
        }
    }

    if (MODE == 2) {
        float sf[4], hf[4], sc[4], hc[4];
#pragma unroll
        for (int j = 0; j < 4; ++j) {
            const int col = tx * 4 + j;
            sf[j] = scales[256 + col];      hf[j] = scales[384 + col];
            sc[j] = scales[256 + 64 + col]; hc[j] = scales[384 + 64 + col];
        }
#pragma unroll
        for (int i = 0; i < 8; ++i) {
            if (rowg[i] < NTRIP) {
                const int e = idx_ji[rowg[i]];
                float* dst = &agg[(size_t)e * 64 + tx * 4];
#pragma unroll
                for (int j = 0; j < 4; ++j) {
                    const float f = acc[i][j] * sf[j] + hf[j];
                    const float c = acc[i][j + 4] * sc[j] + hc[j];
                    atomicAdd(dst + j, sigmoid_f(f) * tanh_f(c));
                }
            }
        }
    }
}

// ---------------------------------------------------------------------------
// c2 GEMM: C(E,128) = (node[i]*node[j]) @ W2^T  (K=64)
// MODE 0: column stats only.
// MODE 2: BN + gate -> u, store u (E x 64) to uout, accumulate u column stats.
// ---------------------------------------------------------------------------
template <int MODE>
__global__ __launch_bounds__(256) void k_gemm_c2(
    const float* __restrict__ node, const int* __restrict__ vi,
    const int* __restrict__ vj, const float* __restrict__ W2,
    float* __restrict__ gsum, float* __restrict__ gsq,
    const float* __restrict__ scales, float* __restrict__ uout,
    float* __restrict__ usum, float* __restrict__ usq)
{
    __shared__ float sA[32][132];
    __shared__ float sB[32][132];
    __shared__ float sstat[256];

    const int tid = threadIdx.x;
    const int tx = tid & 15, ty = tid >> 4;
    const int bm = blockIdx.x * 128;

    float acc[8][8];
#pragma unroll
    for (int i = 0; i < 8; ++i)
#pragma unroll
        for (int j = 0; j < 8; ++j) acc[i][j] = 0.0f;

    const int mstage = tid >> 1;
    const int kq = (tid & 1) * 16;
    int g = bm + mstage;
    if (g >= NEDGE) g = NEDGE - 1;
    const int r0 = vi[g], r1 = vj[g];

    for (int s = 0; s < 2; ++s) {
        const int kin = s * 32;
        const float4* pa = reinterpret_cast<const float4*>(node + (size_t)r0 * 64 + kin + kq);
        const float4* pc = reinterpret_cast<const float4*>(node + (size_t)r1 * 64 + kin + kq);
        float4 v0 = pa[0], v1 = pa[1], v2 = pa[2], v3 = pa[3];
        float4 u0 = pc[0], u1 = pc[1], u2 = pc[2], u3 = pc[3];
        const float4* pb = reinterpret_cast<const float4*>(W2 + (size_t)mstage * 64 + kin + kq);
        float4 w0 = pb[0], w1 = pb[1], w2 = pb[2], w3 = pb[3];

        __syncthreads();
        const float va[16] = {v0.x*u0.x, v0.y*u0.y, v0.z*u0.z, v0.w*u0.w,
                              v1.x*u1.x, v1.y*u1.y, v1.z*u1.z, v1.w*u1.w,
                              v2.x*u2.x, v2.y*u2.y, v2.z*u2.z, v2.w*u2.w,
                              v3.x*u3.x, v3.y*u3.y, v3.z*u3.z, v3.w*u3.w};
        const float vb[16] = {w0.x,w0.y,w0.z,w0.w, w1.x,w1.y,w1.z,w1.w,
                              w2.x,w2.y,w2.z,w2.w, w3.x,w3.y,w3.z,w3.w};
#pragma unroll
        for (int u = 0; u < 16; ++u) sA[kq + u][mstage] = va[u];
#pragma unroll
        for (int u = 0; u < 16; ++u) sB[kq + u][mstage] = vb[u];
        __syncthreads();

#pragma unroll 4
        for (int k = 0; k < 32; ++k) {
            const float4 a0 = *reinterpret_cast<const float4*>(&sA[k][ty * 4]);
            const float4 a1 = *reinterpret_cast<const float4*>(&sA[k][64 + ty * 4]);
            const float4 b0 = *reinterpret_cast<const float4*>(&sB[k][tx * 4]);
            const float4 b1 = *reinterpret_cast<const float4*>(&sB[k][64 + tx * 4]);
            const float av[8] = {a0.x,a0.y,a0.z,a0.w, a1.x,a1.y,a1.z,a1.w};
            const float bv[8] = {b0.x,b0.y,b0.z,b0.w, b1.x,b1.y,b1.z,b1.w};
#pragma unroll
            for (int i = 0; i < 8; ++i)
#pragma unroll
                for (int j = 0; j < 8; ++j)
                    acc[i][j] = fmaf(av[i], bv[j], acc[i][j]);
        }
    }

    int rowg[8];
#pragma unroll
    for (int i = 0; i < 8; ++i) {
        const int m = (i < 4) ? (ty * 4 + i) : (64 + ty * 4 + (i - 4));
        rowg[i] = bm + m;
    }

    if (MODE == 0) {
        __syncthreads();
        sstat[tid] = 0.0f;
        __syncthreads();
#pragma unroll
        for (int j = 0; j < 8; ++j) {
            const int n = (j < 4) ? (tx * 4 + j) : (64 + tx * 4 + (j - 4));
            float s = 0.0f, q = 0.0f;
#pragma unroll
            for (int i = 0; i < 8; ++i) {
                if (rowg[i] < NEDGE) { s += acc[i][j]; q += acc[i][j] * acc[i][j]; }
            }
            atomicAdd(&sstat[n], s);
            atomicAdd(&sstat[128 + n], q);
        }
        __syncthreads();
        if (tid < 128) {
            atomicAdd(&gsum[tid], sstat[tid]);
            atomicAdd(&gsq[tid], sstat[128 + tid]);
        }
    }

    if (MODE == 2) {
        float sf[4], hf[4], sc[4], hc[4];
#pragma unroll
        for (int j = 0; j < 4; ++j) {
            const int col = tx * 4 + j;
            sf[j] = scales[col];      hf[j] = scales[128 + col];
            sc[j] = scales[64 + col]; hc[j] = scales[128 + 64 + col];
        }
        __syncthreads();
        sstat[tid] = 0.0f;
        __syncthreads();
        float lsum[4] = {0, 0, 0, 0}, lsq[4] = {0, 0, 0, 0};
#pragma unroll
        for (int i = 0; i < 8; ++i) {
            if (rowg[i] < NEDGE) {
                float uv[4];
#pragma unroll
                for (int j = 0; j < 4; ++j) {
                    const float f = acc[i][j] * sf[j] + hf[j];
                    const float c = acc[i][j + 4] * sc[j] + hc[j];
                    uv[j] = sigmoid_f(f) * tanh_f(c);
                    lsum[j] += uv[j]; lsq[j] += uv[j] * uv[j];
                }
                *reinterpret_cast<float4*>(&uout[(size_t)rowg[i] * 64 + tx * 4]) =
                    make_float4(uv[0], uv[1], uv[2], uv[3]);
            }
        }
#pragma unroll
        for (int j = 0; j < 4; ++j) {
            atomicAdd(&sstat[tx * 4 + j], lsum[j]);
            atomicAdd(&sstat[128 + tx * 4 + j], lsq[j]);
        }
        __syncthreads();
        if (tid < 64) {
            atomicAdd(&usum[tid], sstat[tid]);
            atomicAdd(&usq[tid], sstat[128 + tid]);
        }
    }
}

// ---------------------------------------------------------------------------
__global__ void k_finalize1(const float* __restrict__ gstats,
                            const float* __restrict__ g_c2, const float* __restrict__ beta_c2,
                            const float* __restrict__ g_c3, const float* __restrict__ beta_c3,
                            float* __restrict__ scales)
{
    const int t = threadIdx.x;
    if (t < 128) {
        const float inv = 1.0f / (float)NEDGE;
        const float mean = gstats[t] * inv;
        const float var = gstats[128 + t] * inv - mean * mean;
        const float sc = g_c2[t] * rsqrtf(var + EPSBN);
        scales[t] = sc;
        scales[128 + t] = beta_c2[t] - mean * sc;
    } else {
        const int c = t - 128;
        const float inv = 1.0f / (float)NTRIP;
        const float mean = gstats[256 + c] * inv;
        const float var = gstats[384 + c] * inv - mean * mean;
        const float sc = g_c3[c] * rsqrtf(var + EPSBN);
        scales[256 + c] = sc;
        scales[384 + c] = beta_c3[c] - mean * sc;
    }
}

__global__ void k_finalize2(const float* __restrict__ gstats,
                            const float* __restrict__ g_c22, const float* __restrict__ beta_c22,
                            const float* __restrict__ g_c32, const float* __restrict__ beta_c32,
                            float* __restrict__ scales)
{
    const int t = threadIdx.x;
    const float inv = 1.0f / (float)NEDGE;
    if (t < 64) {
        const float mean = gstats[512 + t] * inv;
        const float var = gstats[576 + t] * inv - mean * mean;
        const float sc = g_c22[t] * rsqrtf(var + EPSBN);
        scales[512 + t] = sc;
        scales[576 + t] = beta_c22[t] - mean * sc;
    } else {
        const int c = t - 64;
        const float mean = gstats[640 + c] * inv;
        const float var = gstats[704 + c] * inv - mean * mean;
        const float sc = g_c32[c] * rsqrtf(var + EPSBN);
        scales[640 + c] = sc;
        scales[704 + c] = beta_c32[c] - mean * sc;
    }
}

// ---------------------------------------------------------------------------
// fast path only: gate c3_lin from buffer + scatter into agg
// ---------------------------------------------------------------------------
__global__ __launch_bounds__(256) void k_act3(
    const float* __restrict__ c3_lin, const float* __restrict__ scales,
    const int* __restrict__ idx_ji, float* __restrict__ agg)
{
    const int tid = threadIdx.x;
    const int c4 = tid & 15;
    float sf[4], hf[4], sc[4], hc[4];
#pragma unroll
    for (int cc = 0; cc < 4; ++cc) {
        const int col = c4 * 4 + cc;
        sf[cc] = scales[256 + col];      hf[cc] = scales[384 + col];
        sc[cc] = scales[256 + 64 + col]; hc[cc] = scales[384 + 64 + col];
    }
    const long total = (long)NTRIP * 16;
    const long stride = (long)gridDim.x * blockDim.x;
    for (long idx = (long)blockIdx.x * blockDim.x + tid; idx < total; idx += stride) {
        const int row = (int)(idx >> 4);
        const float4 f = *reinterpret_cast<const float4*>(&c3_lin[(size_t)row * 128 + c4 * 4]);
        const float4 c = *reinterpret_cast<const float4*>(&c3_lin[(size_t)row * 128 + 64 + c4 * 4]);
        float mv[4];
        mv[0] = sigmoid_f(f.x * sf[0] + hf[0]) * tanh_f(c.x * sc[0] + hc[0]);
        mv[1] = sigmoid_f(f.y * sf[1] + hf[1]) * tanh_f(c.y * sc[1] + hc[1]);
        mv[2] = sigmoid_f(f.z * sf[2] + hf[2]) * tanh_f(c.z * sc[2] + hc[2]);
        mv[3] = sigmoid_f(f.w * sf[3] + hf[3]) * tanh_f(c.w * sc[3] + hc[3]);
        const int e = idx_ji[row];
        float* dst = &agg[(size_t)e * 64 + c4 * 4];
        atomicAdd(dst + 0, mv[0]);
        atomicAdd(dst + 1, mv[1]);
        atomicAdd(dst + 2, mv[2]);
        atomicAdd(dst + 3, mv[3]);
    }
}

// ---------------------------------------------------------------------------
__global__ __launch_bounds__(256) void k_stats_agg(
    const float* __restrict__ agg, float* __restrict__ gstats)
{
    const int tid = threadIdx.x;
    const int c4 = tid & 15;
    float ls[4] = {0, 0, 0, 0}, lq[4] = {0, 0, 0, 0};
    const long total = (long)NEDGE * 16;
    const long stride = (long)gridDim.x * blockDim.x;
    for (long idx = (long)blockIdx.x * blockDim.x + tid; idx < total; idx += stride) {
        const int row = (int)(idx >> 4);
        const float4 a = *reinterpret_cast<const float4*>(&agg[(size_t)row * 64 + c4 * 4]);
        ls[0] += a.x; lq[0] += a.x * a.x;
        ls[1] += a.y; lq[1] += a.y * a.y;
        ls[2] += a.z; lq[2] += a.z * a.z;
        ls[3] += a.w; lq[3] += a.w * a.w;
    }
    __shared__ float red[2][16][68];
    const int gr = tid >> 4;
#pragma unroll
    for (int cc = 0; cc < 4; ++cc) {
        red[0][gr][c4 * 4 + cc] = ls[cc];
        red[1][gr][c4 * 4 + cc] = lq[cc];
    }
    __syncthreads();
    if (tid < 64) {
        float s = 0.0f, q = 0.0f;
        for (int g2 = 0; g2 < 16; ++g2) { s += red[0][g2][tid]; q += red[1][g2][tid]; }
        atomicAdd(&gstats[640 + tid], s);
        atomicAdd(&gstats[704 + tid], q);
    }
}

// ---------------------------------------------------------------------------
// out = tanh(edge + BN22(u) + BN32(agg));  u lives in d_out, overwritten here
// ---------------------------------------------------------------------------
__global__ __launch_bounds__(256) void k_final(
    const float* __restrict__ edge, const float* __restrict__ agg,
    const float* __restrict__ scales, float* __restrict__ out)
{
    const int tid = threadIdx.x;
    const int c4 = tid & 15;
    float su[4], hu[4], sa[4], ha[4];
#pragma unroll
    for (int cc = 0; cc < 4; ++cc) {
        const int col = c4 * 4 + cc;
        su[cc] = scales[512 + col]; hu[cc] = scales[576 + col];
        sa[cc] = scales[640 + col]; ha[cc] = scales[704 + col];
    }
    const long total = (long)NEDGE * 16;
    const long stride = (long)gridDim.x * blockDim.x;
    for (long idx = (long)blockIdx.x * blockDim.x + tid; idx < total; idx += stride) {
        const int row = (int)(idx >> 4);
        const size_t base = (size_t)row * 64 + c4 * 4;
        const float4 e = *reinterpret_cast<const float4*>(&edge[base]);
        const float4 u = *reinterpret_cast<const float4*>(&out[base]);
        const float4 a = *reinterpret_cast<const float4*>(&agg[base]);
        float4 o;
        o.x = tanh_f(e.x + u.x * su[0] + hu[0] + a.x * sa[0] + ha[0]);
        o.y = tanh_f(e.y + u.y * su[1] + hu[1] + a.y * sa[1] + ha[1]);
        o.z = tanh_f(e.z + u.z * su[2] + hu[2] + a.z * sa[2] + ha[2]);
        o.w = tanh_f(e.w + u.w * su[3] + hu[3] + a.w * sa[3] + ha[3]);
        *reinterpret_cast<float4*>(&out[base]) = o;
    }
}

// ---------------------------------------------------------------------------
extern "C" void kernel_launch(void* const* d_in, const int* in_sizes, int n_in,
                              void* d_out, int out_size, void* d_ws, size_t ws_size,
                              hipStream_t stream)
{
    (void)in_sizes; (void)n_in; (void)out_size;
    const float* node   = (const float*)d_in[0];
    const float* edge   = (const float*)d_in[1];
    const int*   vi     = (const int*)d_in[2];
    const int*   vj     = (const int*)d_in[3];
    const int*   idx_i  = (const int*)d_in[4];
    const int*   idx_j  = (const int*)d_in[5];
    const int*   idx_k  = (const int*)d_in[6];
    const int*   idx_ji = (const int*)d_in[7];
    const int*   idx_kj = (const int*)d_in[8];
    const float* W2     = (const float*)d_in[9];
    // d_in[10] = b2: cancels inside BN (mean subtraction)
    const float* W3     = (const float*)d_in[11];
    // d_in[12] = b3: cancels inside BN
    const float* g_c2    = (const float*)d_in[13];
    const float* beta_c2 = (const float*)d_in[14];
    const float* g_c3    = (const float*)d_in[15];
    const float* beta_c3 = (const float*)d_in[16];
    const float* g_c22    = (const float*)d_in[17];
    const float* beta_c22 = (const float*)d_in[18];
    const float* g_c32    = (const float*)d_in[19];
    const float* beta_c32 = (const float*)d_in[20];
    float* out = (float*)d_out;

    float* ws     = (float*)d_ws;
    float* gstats = ws;                        // 768 floats
    float* scales = ws + 768;                  // 768 floats
    float* agg    = ws + 1536;                 // E*64 floats
    float* c3_lin = agg + (size_t)NEDGE * 64;  // T*128 floats (fast path only)

    const size_t need_slow = (1536 + (size_t)NEDGE * 64) * sizeof(float);         // ~51.2 MB
    const size_t need_fast = need_slow + (size_t)NTRIP * 128 * sizeof(float);     // ~358 MB
    const bool fast = (ws_size >= need_fast);
    (void)need_slow;

    hipMemsetAsync(gstats, 0, 768 * sizeof(float), stream);
    hipMemsetAsync(agg, 0, (size_t)NEDGE * 64 * sizeof(float), stream);

    const int grid_c2 = (NEDGE + 127) / 128;
    const int grid_c3 = (NTRIP + 127) / 128;

    // pass 1: column stats of both linear outputs
    k_gemm_c2<0><<<grid_c2, 256, 0, stream>>>(
        node, vi, vj, W2, gstats + 0, gstats + 128, nullptr, nullptr, nullptr, nullptr);
    if (fast) {
        k_gemm_c3<1><<<grid_c3, 256, 0, stream>>>(
            node, edge, idx_i, idx_j, idx_k, idx_ji, idx_kj, W3,
            c3_lin, gstats + 256, gstats + 384, nullptr, nullptr);
    } else {
        k_gemm_c3<0><<<grid_c3, 256, 0, stream>>>(
            node, edge, idx_i, idx_j, idx_k, idx_ji, idx_kj, W3,
            nullptr, gstats + 256, gstats + 384, nullptr, nullptr);
    }
    k_finalize1<<<1, 256, 0, stream>>>(gstats, g_c2, beta_c2, g_c3, beta_c3, scales);

    // pass 2: apply BN + gates; u -> d_out (scratch), msg -> agg (atomics)
    k_gemm_c2<2><<<grid_c2, 256, 0, stream>>>(
        node, vi, vj, W2, nullptr, nullptr, scales, out, gstats + 512, gstats + 576);
    if (fast) {
        k_act3<<<3072, 256, 0, stream>>>(c3_lin, scales, idx_ji, agg);
    } else {
        k_gemm_c3<2><<<grid_c3, 256, 0, stream>>>(
            node, edge, idx_i, idx_j, idx_k, idx_ji, idx_kj, W3,
            nullptr, nullptr, nullptr, scales, agg);
    }

    k_stats_agg<<<3072, 256, 0, stream>>>(agg, gstats);
    k_finalize2<<<1, 128, 0, stream>>>(gstats, g_c22, beta_c22, g_c32, beta_c32, scales);
    k_final<<<3072, 256, 0, stream>>>(edge, agg, scales, out);
}

// Round 3
// 841.203 us; speedup vs baseline: 2.1600x; 2.1600x over previous
//
#include <hip/hip_runtime.h>
#include <cstdint>

#define HN 64
#define HE 64
#define NNODE 50000
#define NEDGE 200000
#define NTRIP 600000
#define EPSBN 1e-5f

// gstats layout (floats): c2_sum(128) c2_sq(128) c3_sum(128) c3_sq(128)
//                         u_sum(64) u_sq(64) agg_sum(64) agg_sq(64)   = 768
// scales layout (floats): c2_scale(128) c2_shift(128) c3_scale(128) c3_shift(128)
//                         u_scale(64) u_shift(64) agg_scale(64) agg_shift(64) = 768

typedef __attribute__((ext_vector_type(8))) short short8;
typedef __attribute__((ext_vector_type(4))) float f32x4;

__device__ __forceinline__ float sigmoid_f(float x) {
    return 1.0f / (1.0f + __expf(-x));
}
__device__ __forceinline__ float tanh_f(float x) {
    return 1.0f - 2.0f / (__expf(2.0f * x) + 1.0f);
}

__device__ __forceinline__ short8 as_s8(uint4 v) {
    union { uint4 u; short8 s; } c; c.u = v; return c.s;
}

// convert 16 fp32 -> 8 packed-u32 of bf16-hi (and optionally bf16-lo), write to LDS
__device__ __forceinline__ void cvt_store16(
    float4 x0, float4 x1, float4 x2, float4 x3,
    unsigned int* __restrict__ dhi, unsigned int* __restrict__ dlo, bool do_lo)
{
    float xv[16] = {x0.x, x0.y, x0.z, x0.w, x1.x, x1.y, x1.z, x1.w,
                    x2.x, x2.y, x2.z, x2.w, x3.x, x3.y, x3.z, x3.w};
    unsigned hu[16];
#pragma unroll
    for (int e = 0; e < 16; ++e) hu[e] = __float_as_uint(xv[e]) >> 16;  // truncate split
#pragma unroll
    for (int m = 0; m < 8; ++m) dhi[m] = (hu[2 * m + 1] << 16) | hu[2 * m];
    if (do_lo) {
        unsigned lu[16];
#pragma unroll
        for (int e = 0; e < 16; ++e) {
            const float hf = __uint_as_float(hu[e] << 16);
            lu[e] = __float_as_uint(xv[e] - hf) >> 16;  // exact residual, trunc to bf16
        }
#pragma unroll
        for (int m = 0; m < 8; ++m) dlo[m] = (lu[2 * m + 1] << 16) | lu[2 * m];
    }
}

// ---------------------------------------------------------------------------
// c3 GEMM via bf16 MFMA, split precision.
// C(T,128) = concat(node[ii],node[ij],node[ik],edge[ji],edge[kj]) @ W3^T
// BM=128 rows/block, 4 waves, each wave: 32 rows x 128 cols (2x8 tiles of
// 16x16, mfma_f32_16x16x32_bf16). K=320 in 10 chunks of 32.
// MODE 0: 1-term bf16 (stats only, column sum/sumsq -> gsum/gsq).
// MODE 2: 3-term split (ah*bh + ah*bl + al*bh), BN + gate + scatter to agg.
// ---------------------------------------------------------------------------
template <int MODE>
__global__ __launch_bounds__(256) void k_gemm_c3_mfma(
    const float* __restrict__ node, const float* __restrict__ edge,
    const int* __restrict__ idx_i, const int* __restrict__ idx_j,
    const int* __restrict__ idx_k, const int* __restrict__ idx_ji,
    const int* __restrict__ idx_kj, const float* __restrict__ W3,
    float* __restrict__ gsum, float* __restrict__ gsq,
    const float* __restrict__ scales, float* __restrict__ agg)
{
    constexpr int TERMS = (MODE == 0) ? 1 : 3;
    constexpr int LDA = 20;                    // u32 stride per row (16 + pad, 16B-aligned)
    constexpr int PLANE = 128 * LDA;           // one hi or lo plane

    __shared__ unsigned int sA[PLANE * ((TERMS == 1) ? 1 : 2)];
    __shared__ unsigned int sB[PLANE * ((TERMS == 1) ? 1 : 2)];
    __shared__ float sstat[256];

    const int tid = threadIdx.x;
    const int lane = tid & 63;
    const int w = tid >> 6;       // wave 0..3
    const int quad = lane >> 4;   // 0..3
    const int l16 = lane & 15;
    const int bm = blockIdx.x * 128;

    // staging role: 2 threads per tile-row, 16 elements each
    const int srow = tid >> 1;
    const int shalf = tid & 1;
    int g = bm + srow;
    if (g >= NTRIP) g = NTRIP - 1;
    const int r0 = idx_i[g], r1 = idx_j[g], r2 = idx_k[g];
    const int r3 = idx_ji[g], r4 = idx_kj[g];

    f32x4 acc[2][8];
#pragma unroll
    for (int mi = 0; mi < 2; ++mi)
#pragma unroll
        for (int ni = 0; ni < 8; ++ni) acc[mi][ni] = (f32x4){0.f, 0.f, 0.f, 0.f};

    for (int s = 0; s < 10; ++s) {
        const int seg = s >> 1;
        const int kin = (s & 1) * 32;
        const float* src;
        switch (seg) {
            case 0: src = node + (size_t)r0 * 64; break;
            case 1: src = node + (size_t)r1 * 64; break;
            case 2: src = node + (size_t)r2 * 64; break;
            case 3: src = edge + (size_t)r3 * 64; break;
            default: src = edge + (size_t)r4 * 64; break;
        }
        const float4* pa = reinterpret_cast<const float4*>(src + kin + shalf * 16);
        float4 a0 = pa[0], a1 = pa[1], a2 = pa[2], a3 = pa[3];
        const float4* pb = reinterpret_cast<const float4*>(
            W3 + (size_t)srow * 320 + seg * 64 + kin + shalf * 16);
        float4 b0 = pb[0], b1 = pb[1], b2 = pb[2], b3 = pb[3];

        __syncthreads();  // prior iteration's fragment reads done
        {
            unsigned int* dA = sA + srow * LDA + shalf * 8;
            unsigned int* dB = sB + srow * LDA + shalf * 8;
            cvt_store16(a0, a1, a2, a3, dA, dA + PLANE, TERMS == 3);
            cvt_store16(b0, b1, b2, b3, dB, dB + PLANE, TERMS == 3);
        }
        __syncthreads();

        // fragments: A rows = w*32 + mi*16 + l16 ; k-chunk = quad*4 u32
        uint4 ahi[2], alo[2];
#pragma unroll
        for (int mi = 0; mi < 2; ++mi) {
            const int abase = (w * 32 + mi * 16 + l16) * LDA + quad * 4;
            ahi[mi] = *reinterpret_cast<const uint4*>(&sA[abase]);
            if (TERMS == 3) alo[mi] = *reinterpret_cast<const uint4*>(&sA[PLANE + abase]);
        }
#pragma unroll
        for (int ni = 0; ni < 8; ++ni) {
            const int bbase = (ni * 16 + l16) * LDA + quad * 4;
            const uint4 bhi = *reinterpret_cast<const uint4*>(&sB[bbase]);
#pragma unroll
            for (int mi = 0; mi < 2; ++mi)
                acc[mi][ni] = __builtin_amdgcn_mfma_f32_16x16x32_bf16(
                    as_s8(ahi[mi]), as_s8(bhi), acc[mi][ni], 0, 0, 0);
            if (TERMS == 3) {
                const uint4 blo = *reinterpret_cast<const uint4*>(&sB[PLANE + bbase]);
#pragma unroll
                for (int mi = 0; mi < 2; ++mi) {
                    acc[mi][ni] = __builtin_amdgcn_mfma_f32_16x16x32_bf16(
                        as_s8(ahi[mi]), as_s8(blo), acc[mi][ni], 0, 0, 0);
                    acc[mi][ni] = __builtin_amdgcn_mfma_f32_16x16x32_bf16(
                        as_s8(alo[mi]), as_s8(bhi), acc[mi][ni], 0, 0, 0);
                }
            }
        }
    }

    // C/D layout: col = ni*16 + l16, row = w*32 + mi*16 + quad*4 + reg
    if (MODE == 0) {
        __syncthreads();
        sstat[tid] = 0.0f;
        __syncthreads();
#pragma unroll
        for (int ni = 0; ni < 8; ++ni) {
            const int col = ni * 16 + l16;
            float s = 0.0f, q = 0.0f;
#pragma unroll
            for (int mi = 0; mi < 2; ++mi)
#pragma unroll
                for (int reg = 0; reg < 4; ++reg) {
                    const int grow = bm + w * 32 + mi * 16 + quad * 4 + reg;
                    if (grow < NTRIP) {
                        const float v = acc[mi][ni][reg];
                        s += v; q += v * v;
                    }
                }
            atomicAdd(&sstat[col], s);
            atomicAdd(&sstat[128 + col], q);
        }
        __syncthreads();
        if (tid < 128) {
            atomicAdd(&gsum[tid], sstat[tid]);
            atomicAdd(&gsq[tid], sstat[128 + tid]);
        }
    }

    if (MODE == 2) {
        float sf[4], hf[4], sc[4], hc[4];
#pragma unroll
        for (int ni = 0; ni < 4; ++ni) {
            const int col = ni * 16 + l16;
            sf[ni] = scales[256 + col];      hf[ni] = scales[384 + col];
            sc[ni] = scales[256 + 64 + col]; hc[ni] = scales[384 + 64 + col];
        }
#pragma unroll
        for (int mi = 0; mi < 2; ++mi)
#pragma unroll
            for (int reg = 0; reg < 4; ++reg) {
                const int grow = bm + w * 32 + mi * 16 + quad * 4 + reg;
                if (grow < NTRIP) {
                    const int e = idx_ji[grow];
                    float* dst = &agg[(size_t)e * 64 + l16];
#pragma unroll
                    for (int ni = 0; ni < 4; ++ni) {
                        const float fv = acc[mi][ni][reg] * sf[ni] + hf[ni];
                        const float cv = acc[mi][ni + 4][reg] * sc[ni] + hc[ni];
                        atomicAdd(dst + ni * 16, sigmoid_f(fv) * tanh_f(cv));
                    }
                }
            }
    }
}

// ---------------------------------------------------------------------------
// c2 GEMM: C(E,128) = (node[i]*node[j]) @ W2^T  (K=64)  [VALU, unchanged]
// MODE 0: column stats only.
// MODE 2: BN + gate -> u, store u (E x 64) to uout, accumulate u column stats.
// ---------------------------------------------------------------------------
template <int MODE>
__global__ __launch_bounds__(256) void k_gemm_c2(
    const float* __restrict__ node, const int* __restrict__ vi,
    const int* __restrict__ vj, const float* __restrict__ W2,
    float* __restrict__ gsum, float* __restrict__ gsq,
    const float* __restrict__ scales, float* __restrict__ uout,
    float* __restrict__ usum, float* __restrict__ usq)
{
    __shared__ float sA[32][132];
    __shared__ float sB[32][132];
    __shared__ float sstat[256];

    const int tid = threadIdx.x;
    const int tx = tid & 15, ty = tid >> 4;
    const int bm = blockIdx.x * 128;

    float acc[8][8];
#pragma unroll
    for (int i = 0; i < 8; ++i)
#pragma unroll
        for (int j = 0; j < 8; ++j) acc[i][j] = 0.0f;

    const int mstage = tid >> 1;
    const int kq = (tid & 1) * 16;
    int g = bm + mstage;
    if (g >= NEDGE) g = NEDGE - 1;
    const int r0 = vi[g], r1 = vj[g];

    for (int s = 0; s < 2; ++s) {
        const int kin = s * 32;
        const float4* pa = reinterpret_cast<const float4*>(node + (size_t)r0 * 64 + kin + kq);
        const float4* pc = reinterpret_cast<const float4*>(node + (size_t)r1 * 64 + kin + kq);
        float4 v0 = pa[0], v1 = pa[1], v2 = pa[2], v3 = pa[3];
        float4 u0 = pc[0], u1 = pc[1], u2 = pc[2], u3 = pc[3];
        const float4* pb = reinterpret_cast<const float4*>(W2 + (size_t)mstage * 64 + kin + kq);
        float4 w0 = pb[0], w1 = pb[1], w2 = pb[2], w3 = pb[3];

        __syncthreads();
        const float va[16] = {v0.x*u0.x, v0.y*u0.y, v0.z*u0.z, v0.w*u0.w,
                              v1.x*u1.x, v1.y*u1.y, v1.z*u1.z, v1.w*u1.w,
                              v2.x*u2.x, v2.y*u2.y, v2.z*u2.z, v2.w*u2.w,
                              v3.x*u3.x, v3.y*u3.y, v3.z*u3.z, v3.w*u3.w};
        const float vb[16] = {w0.x,w0.y,w0.z,w0.w, w1.x,w1.y,w1.z,w1.w,
                              w2.x,w2.y,w2.z,w2.w, w3.x,w3.y,w3.z,w3.w};
#pragma unroll
        for (int u = 0; u < 16; ++u) sA[kq + u][mstage] = va[u];
#pragma unroll
        for (int u = 0; u < 16; ++u) sB[kq + u][mstage] = vb[u];
        __syncthreads();

#pragma unroll 4
        for (int k = 0; k < 32; ++k) {
            const float4 a0 = *reinterpret_cast<const float4*>(&sA[k][ty * 4]);
            const float4 a1 = *reinterpret_cast<const float4*>(&sA[k][64 + ty * 4]);
            const float4 b0 = *reinterpret_cast<const float4*>(&sB[k][tx * 4]);
            const float4 b1 = *reinterpret_cast<const float4*>(&sB[k][64 + tx * 4]);
            const float av[8] = {a0.x,a0.y,a0.z,a0.w, a1.x,a1.y,a1.z,a1.w};
            const float bv[8] = {b0.x,b0.y,b0.z,b0.w, b1.x,b1.y,b1.z,b1.w};
#pragma unroll
            for (int i = 0; i < 8; ++i)
#pragma unroll
                for (int j = 0; j < 8; ++j)
                    acc[i][j] = fmaf(av[i], bv[j], acc[i][j]);
        }
    }

    int rowg[8];
#pragma unroll
    for (int i = 0; i < 8; ++i) {
        const int m = (i < 4) ? (ty * 4 + i) : (64 + ty * 4 + (i - 4));
        rowg[i] = bm + m;
    }

    if (MODE == 0) {
        __syncthreads();
        sstat[tid] = 0.0f;
        __syncthreads();
#pragma unroll
        for (int j = 0; j < 8; ++j) {
            const int n = (j < 4) ? (tx * 4 + j) : (64 + tx * 4 + (j - 4));
            float s = 0.0f, q = 0.0f;
#pragma unroll
            for (int i = 0; i < 8; ++i) {
                if (rowg[i] < NEDGE) { s += acc[i][j]; q += acc[i][j] * acc[i][j]; }
            }
            atomicAdd(&sstat[n], s);
            atomicAdd(&sstat[128 + n], q);
        }
        __syncthreads();
        if (tid < 128) {
            atomicAdd(&gsum[tid], sstat[tid]);
            atomicAdd(&gsq[tid], sstat[128 + tid]);
        }
    }

    if (MODE == 2) {
        float sf[4], hf[4], sc[4], hc[4];
#pragma unroll
        for (int j = 0; j < 4; ++j) {
            const int col = tx * 4 + j;
            sf[j] = scales[col];      hf[j] = scales[128 + col];
            sc[j] = scales[64 + col]; hc[j] = scales[128 + 64 + col];
        }
        __syncthreads();
        sstat[tid] = 0.0f;
        __syncthreads();
        float lsum[4] = {0, 0, 0, 0}, lsq[4] = {0, 0, 0, 0};
#pragma unroll
        for (int i = 0; i < 8; ++i) {
            if (rowg[i] < NEDGE) {
                float uv[4];
#pragma unroll
                for (int j = 0; j < 4; ++j) {
                    const float f = acc[i][j] * sf[j] + hf[j];
                    const float c = acc[i][j + 4] * sc[j] + hc[j];
                    uv[j] = sigmoid_f(f) * tanh_f(c);
                    lsum[j] += uv[j]; lsq[j] += uv[j] * uv[j];
                }
                *reinterpret_cast<float4*>(&uout[(size_t)rowg[i] * 64 + tx * 4]) =
                    make_float4(uv[0], uv[1], uv[2], uv[3]);
            }
        }
#pragma unroll
        for (int j = 0; j < 4; ++j) {
            atomicAdd(&sstat[tx * 4 + j], lsum[j]);
            atomicAdd(&sstat[128 + tx * 4 + j], lsq[j]);
        }
        __syncthreads();
        if (tid < 64) {
            atomicAdd(&usum[tid], sstat[tid]);
            atomicAdd(&usq[tid], sstat[128 + tid]);
        }
    }
}

// ---------------------------------------------------------------------------
__global__ void k_finalize1(const float* __restrict__ gstats,
                            const float* __restrict__ g_c2, const float* __restrict__ beta_c2,
                            const float* __restrict__ g_c3, const float* __restrict__ beta_c3,
                            float* __restrict__ scales)
{
    const int t = threadIdx.x;
    if (t < 128) {
        const float inv = 1.0f / (float)NEDGE;
        const float mean = gstats[t] * inv;
        const float var = gstats[128 + t] * inv - mean * mean;
        const float sc = g_c2[t] * rsqrtf(var + EPSBN);
        scales[t] = sc;
        scales[128 + t] = beta_c2[t] - mean * sc;
    } else {
        const int c = t - 128;
        const float inv = 1.0f / (float)NTRIP;
        const float mean = gstats[256 + c] * inv;
        const float var = gstats[384 + c] * inv - mean * mean;
        const float sc = g_c3[c] * rsqrtf(var + EPSBN);
        scales[256 + c] = sc;
        scales[384 + c] = beta_c3[c] - mean * sc;
    }
}

__global__ void k_finalize2(const float* __restrict__ gstats,
                            const float* __restrict__ g_c22, const float* __restrict__ beta_c22,
                            const float* __restrict__ g_c32, const float* __restrict__ beta_c32,
                            float* __restrict__ scales)
{
    const int t = threadIdx.x;
    const float inv = 1.0f / (float)NEDGE;
    if (t < 64) {
        const float mean = gstats[512 + t] * inv;
        const float var = gstats[576 + t] * inv - mean * mean;
        const float sc = g_c22[t] * rsqrtf(var + EPSBN);
        scales[512 + t] = sc;
        scales[576 + t] = beta_c22[t] - mean * sc;
    } else {
        const int c = t - 64;
        const float mean = gstats[640 + c] * inv;
        const float var = gstats[704 + c] * inv - mean * mean;
        const float sc = g_c32[c] * rsqrtf(var + EPSBN);
        scales[640 + c] = sc;
        scales[704 + c] = beta_c32[c] - mean * sc;
    }
}

// ---------------------------------------------------------------------------
__global__ __launch_bounds__(256) void k_stats_agg(
    const float* __restrict__ agg, float* __restrict__ gstats)
{
    const int tid = threadIdx.x;
    const int c4 = tid & 15;
    float ls[4] = {0, 0, 0, 0}, lq[4] = {0, 0, 0, 0};
    const long total = (long)NEDGE * 16;
    const long stride = (long)gridDim.x * blockDim.x;
    for (long idx = (long)blockIdx.x * blockDim.x + tid; idx < total; idx += stride) {
        const int row = (int)(idx >> 4);
        const float4 a = *reinterpret_cast<const float4*>(&agg[(size_t)row * 64 + c4 * 4]);
        ls[0] += a.x; lq[0] += a.x * a.x;
        ls[1] += a.y; lq[1] += a.y * a.y;
        ls[2] += a.z; lq[2] += a.z * a.z;
        ls[3] += a.w; lq[3] += a.w * a.w;
    }
    __shared__ float red[2][16][68];
    const int gr = tid >> 4;
#pragma unroll
    for (int cc = 0; cc < 4; ++cc) {
        red[0][gr][c4 * 4 + cc] = ls[cc];
        red[1][gr][c4 * 4 + cc] = lq[cc];
    }
    __syncthreads();
    if (tid < 64) {
        float s = 0.0f, q = 0.0f;
        for (int g2 = 0; g2 < 16; ++g2) { s += red[0][g2][tid]; q += red[1][g2][tid]; }
        atomicAdd(&gstats[640 + tid], s);
        atomicAdd(&gstats[704 + tid], q);
    }
}

// ---------------------------------------------------------------------------
// out = tanh(edge + BN22(u) + BN32(agg));  u lives in d_out, overwritten here
// ---------------------------------------------------------------------------
__global__ __launch_bounds__(256) void k_final(
    const float* __restrict__ edge, const float* __restrict__ agg,
    const float* __restrict__ scales, float* __restrict__ out)
{
    const int tid = threadIdx.x;
    const int c4 = tid & 15;
    float su[4], hu[4], sa[4], ha[4];
#pragma unroll
    for (int cc = 0; cc < 4; ++cc) {
        const int col = c4 * 4 + cc;
        su[cc] = scales[512 + col]; hu[cc] = scales[576 + col];
        sa[cc] = scales[640 + col]; ha[cc] = scales[704 + col];
    }
    const long total = (long)NEDGE * 16;
    const long stride = (long)gridDim.x * blockDim.x;
    for (long idx = (long)blockIdx.x * blockDim.x + tid; idx < total; idx += stride) {
        const int row = (int)(idx >> 4);
        const size_t base = (size_t)row * 64 + c4 * 4;
        const float4 e = *reinterpret_cast<const float4*>(&edge[base]);
        const float4 u = *reinterpret_cast<const float4*>(&out[base]);
        const float4 a = *reinterpret_cast<const float4*>(&agg[base]);
        float4 o;
        o.x = tanh_f(e.x + u.x * su[0] + hu[0] + a.x * sa[0] + ha[0]);
        o.y = tanh_f(e.y + u.y * su[1] + hu[1] + a.y * sa[1] + ha[1]);
        o.z = tanh_f(e.z + u.z * su[2] + hu[2] + a.z * sa[2] + ha[2]);
        o.w = tanh_f(e.w + u.w * su[3] + hu[3] + a.w * sa[3] + ha[3]);
        *reinterpret_cast<float4*>(&out[base]) = o;
    }
}

// ---------------------------------------------------------------------------
extern "C" void kernel_launch(void* const* d_in, const int* in_sizes, int n_in,
                              void* d_out, int out_size, void* d_ws, size_t ws_size,
                              hipStream_t stream)
{
    (void)in_sizes; (void)n_in; (void)out_size; (void)ws_size;
    const float* node   = (const float*)d_in[0];
    const float* edge   = (const float*)d_in[1];
    const int*   vi     = (const int*)d_in[2];
    const int*   vj     = (const int*)d_in[3];
    const int*   idx_i  = (const int*)d_in[4];
    const int*   idx_j  = (const int*)d_in[5];
    const int*   idx_k  = (const int*)d_in[6];
    const int*   idx_ji = (const int*)d_in[7];
    const int*   idx_kj = (const int*)d_in[8];
    const float* W2     = (const float*)d_in[9];
    // d_in[10] = b2: cancels inside BN (mean subtraction)
    const float* W3     = (const float*)d_in[11];
    // d_in[12] = b3: cancels inside BN
    const float* g_c2    = (const float*)d_in[13];
    const float* beta_c2 = (const float*)d_in[14];
    const float* g_c3    = (const float*)d_in[15];
    const float* beta_c3 = (const float*)d_in[16];
    const float* g_c22    = (const float*)d_in[17];
    const float* beta_c22 = (const float*)d_in[18];
    const float* g_c32    = (const float*)d_in[19];
    const float* beta_c32 = (const float*)d_in[20];
    float* out = (float*)d_out;

    float* ws     = (float*)d_ws;
    float* gstats = ws;                        // 768 floats
    float* scales = ws + 768;                  // 768 floats
    float* agg    = ws + 1536;                 // E*64 floats (~51.2 MB total)

    hipMemsetAsync(gstats, 0, 768 * sizeof(float), stream);
    hipMemsetAsync(agg, 0, (size_t)NEDGE * 64 * sizeof(float), stream);

    const int grid_c2 = (NEDGE + 127) / 128;
    const int grid_c3 = (NTRIP + 127) / 128;

    // pass 1: column stats (c3 via 1-term bf16 MFMA — stats need only ~0.1%)
    k_gemm_c2<0><<<grid_c2, 256, 0, stream>>>(
        node, vi, vj, W2, gstats + 0, gstats + 128, nullptr, nullptr, nullptr, nullptr);
    k_gemm_c3_mfma<0><<<grid_c3, 256, 0, stream>>>(
        node, edge, idx_i, idx_j, idx_k, idx_ji, idx_kj, W3,
        gstats + 256, gstats + 384, nullptr, nullptr);
    k_finalize1<<<1, 256, 0, stream>>>(gstats, g_c2, beta_c2, g_c3, beta_c3, scales);

    // pass 2: apply BN + gates; u -> d_out (scratch), msg -> agg (atomics)
    // c3 via 3-term split bf16 MFMA (ah*bh + ah*bl + al*bh, err ~2^-16)
    k_gemm_c2<2><<<grid_c2, 256, 0, stream>>>(
        node, vi, vj, W2, nullptr, nullptr, scales, out, gstats + 512, gstats + 576);
    k_gemm_c3_mfma<2><<<grid_c3, 256, 0, stream>>>(
        node, edge, idx_i, idx_j, idx_k, idx_ji, idx_kj, W3,
        nullptr, nullptr, scales, agg);

    k_stats_agg<<<3072, 256, 0, stream>>>(agg, gstats);
    k_finalize2<<<1, 128, 0, stream>>>(gstats, g_c22, beta_c22, g_c32, beta_c32, scales);
    k_final<<<3072, 256, 0, stream>>>(edge, agg, scales, out);
}